// Round 2
// baseline (178.764 us; speedup 1.0000x reference)
//
#include <hip/hip_runtime.h>
#include <hip/hip_bf16.h>

#define N_RAW  100000
#define MPAD   100032   // 1563 * 64
#define DIM    256
#define OUTD   128
#define KN     10
#define N1N    40960
#define BATCH  4096

typedef __attribute__((ext_vector_type(8))) short bf16x8;
typedef __attribute__((ext_vector_type(4))) float f32x4;

static __device__ inline float b2f(short s) {
  unsigned u = ((unsigned)(unsigned short)s) << 16;
  return __builtin_bit_cast(float, u);
}
static __device__ inline short f2b(float f) {
  unsigned u = __builtin_bit_cast(unsigned, f);
  unsigned r = (u + 0x7fff + ((u >> 16) & 1)) >> 16;  // RNE
  return (short)r;
}

// ---- convert W1/W2 f32 -> bf16 (flat) ----
__global__ void cvt_weights(const float* __restrict__ W1, const float* __restrict__ W2,
                            short* __restrict__ W1b, short* __restrict__ W2b) {
  int i = blockIdx.x * blockDim.x + threadIdx.x;
  if (i < OUTD * 2 * DIM)  W1b[i] = f2b(W1[i]);
  if (i < OUTD * 2 * OUTD) W2b[i] = f2b(W2[i]);
}

// ---- P[100032, 256] = raw[100k,256] @ Wc^T (bf16 out, no relu) ----
// Wc row j (j<128): W1[j][0:256] (self part); row j>=128: W1[j-128][256:512] (agg part)
// mfma_f32_16x16x32_bf16 frags (m89/m91-verified):
//   A: row = lane&15, k = (lane>>4)*8 + e ; B: col = lane&15, same k ; D: col=lane&15, row=(lane>>4)*4+e
__global__ void gemm_P(const float* __restrict__ raw, const short* __restrict__ W1b,
                       short* __restrict__ P) {
  int wave = threadIdx.x >> 6, lane = threadIdx.x & 63;
  int m0 = blockIdx.x * 64 + wave * 16;
  int r16 = lane & 15, kg = lane >> 4;

  f32x4 acc[16];
#pragma unroll
  for (int n = 0; n < 16; ++n) acc[n] = (f32x4){0.f, 0.f, 0.f, 0.f};

  int arow = min(m0 + r16, N_RAW - 1);
  const float* xrow = raw + (size_t)arow * DIM + kg * 8;

#pragma unroll
  for (int k = 0; k < DIM; k += 32) {
    float4 a0 = *(const float4*)(xrow + k);
    float4 a1 = *(const float4*)(xrow + k + 4);
    bf16x8 a;
    a[0] = f2b(a0.x); a[1] = f2b(a0.y); a[2] = f2b(a0.z); a[3] = f2b(a0.w);
    a[4] = f2b(a1.x); a[5] = f2b(a1.y); a[6] = f2b(a1.z); a[7] = f2b(a1.w);
#pragma unroll
    for (int n = 0; n < 16; ++n) {
      int j = n * 16 + r16;
      const short* brow = (j < OUTD) ? W1b + j * (2 * DIM) + (k + kg * 8)
                                     : W1b + (j - OUTD) * (2 * DIM) + DIM + (k + kg * 8);
      bf16x8 b = *(const bf16x8*)brow;
      acc[n] = __builtin_amdgcn_mfma_f32_16x16x32_bf16(a, b, acc[n], 0, 0, 0);
    }
  }

#pragma unroll
  for (int n = 0; n < 16; ++n)
#pragma unroll
    for (int j = 0; j < 4; ++j) {
      int r = m0 + kg * 4 + j;           // < 100032 = MPAD, padded buffer
      int c = n * 16 + r16;
      P[(size_t)r * 256 + c] = f2b(acc[n][j]);
    }
}

// ---- h1[i] = relu(P[nodes1[i]][0:128] + 0.1 * sum_k P[neighs1[i,k]][128:256]) ----
__global__ void gather1(const short* __restrict__ P, const int* __restrict__ nodes1,
                        const int* __restrict__ neighs1, short* __restrict__ h1) {
  int g = threadIdx.x >> 4, t = threadIdx.x & 15;
  int row = blockIdx.x * 16 + g;
  int sn = nodes1[row];
  bf16x8 sv = *(const bf16x8*)(P + (size_t)sn * 256 + t * 8);
  float acc[8];
#pragma unroll
  for (int e = 0; e < 8; ++e) acc[e] = 0.f;
#pragma unroll
  for (int k = 0; k < KN; ++k) {
    int nn = neighs1[row * KN + k];
    bf16x8 nv = *(const bf16x8*)(P + (size_t)nn * 256 + 128 + t * 8);
#pragma unroll
    for (int e = 0; e < 8; ++e) acc[e] += b2f(nv[e]);
  }
  bf16x8 o;
#pragma unroll
  for (int e = 0; e < 8; ++e) o[e] = f2b(fmaxf(b2f(sv[e]) + 0.1f * acc[e], 0.f));
  *(bf16x8*)(h1 + (size_t)row * OUTD + t * 8) = o;
}

// ---- Q[40960, 256] = h1[40960,128] @ W2c^T (bf16, no relu) ----
__global__ void gemm_Q(const short* __restrict__ h1, const short* __restrict__ W2b,
                       short* __restrict__ Q) {
  int wave = threadIdx.x >> 6, lane = threadIdx.x & 63;
  int m0 = blockIdx.x * 64 + wave * 16;
  int r16 = lane & 15, kg = lane >> 4;

  f32x4 acc[16];
#pragma unroll
  for (int n = 0; n < 16; ++n) acc[n] = (f32x4){0.f, 0.f, 0.f, 0.f};

  const short* xrow = h1 + (size_t)(m0 + r16) * OUTD + kg * 8;
#pragma unroll
  for (int k = 0; k < OUTD; k += 32) {
    bf16x8 a = *(const bf16x8*)(xrow + k);
#pragma unroll
    for (int n = 0; n < 16; ++n) {
      int j = n * 16 + r16;
      const short* brow = (j < OUTD) ? W2b + j * (2 * OUTD) + (k + kg * 8)
                                     : W2b + (j - OUTD) * (2 * OUTD) + OUTD + (k + kg * 8);
      bf16x8 b = *(const bf16x8*)brow;
      acc[n] = __builtin_amdgcn_mfma_f32_16x16x32_bf16(a, b, acc[n], 0, 0, 0);
    }
  }

#pragma unroll
  for (int n = 0; n < 16; ++n)
#pragma unroll
    for (int j = 0; j < 4; ++j) {
      int r = m0 + kg * 4 + j;
      int c = n * 16 + r16;
      Q[(size_t)r * 256 + c] = f2b(acc[n][j]);
    }
}

// ---- out[i] = relu(Q[map2[i]][0:128] + 0.1 * sum_k Q[neighs2[i,k]][128:256]) f32 ----
__global__ void gather2(const short* __restrict__ Q, const int* __restrict__ map2,
                        const int* __restrict__ neighs2, float* __restrict__ out) {
  int g = threadIdx.x >> 4, t = threadIdx.x & 15;
  int row = blockIdx.x * 16 + g;
  int sn = map2[row];
  bf16x8 sv = *(const bf16x8*)(Q + (size_t)sn * 256 + t * 8);
  float acc[8];
#pragma unroll
  for (int e = 0; e < 8; ++e) acc[e] = 0.f;
#pragma unroll
  for (int k = 0; k < KN; ++k) {
    int nn = neighs2[row * KN + k];
    bf16x8 nv = *(const bf16x8*)(Q + (size_t)nn * 256 + 128 + t * 8);
#pragma unroll
    for (int e = 0; e < 8; ++e) acc[e] += b2f(nv[e]);
  }
  float* orow = out + (size_t)row * OUTD + t * 8;
  float4 o0, o1;
  o0.x = fmaxf(b2f(sv[0]) + 0.1f * acc[0], 0.f);
  o0.y = fmaxf(b2f(sv[1]) + 0.1f * acc[1], 0.f);
  o0.z = fmaxf(b2f(sv[2]) + 0.1f * acc[2], 0.f);
  o0.w = fmaxf(b2f(sv[3]) + 0.1f * acc[3], 0.f);
  o1.x = fmaxf(b2f(sv[4]) + 0.1f * acc[4], 0.f);
  o1.y = fmaxf(b2f(sv[5]) + 0.1f * acc[5], 0.f);
  o1.z = fmaxf(b2f(sv[6]) + 0.1f * acc[6], 0.f);
  o1.w = fmaxf(b2f(sv[7]) + 0.1f * acc[7], 0.f);
  *(float4*)orow = o0;
  *(float4*)(orow + 4) = o1;
}

extern "C" void kernel_launch(void* const* d_in, const int* in_sizes, int n_in,
                              void* d_out, int out_size, void* d_ws, size_t ws_size,
                              hipStream_t stream) {
  const float* raw     = (const float*)d_in[0];
  const float* W1      = (const float*)d_in[1];
  const float* W2      = (const float*)d_in[2];
  const int*   nodes1  = (const int*)d_in[3];
  const int*   neighs1 = (const int*)d_in[4];
  const int*   map2    = (const int*)d_in[5];
  const int*   neighs2 = (const int*)d_in[6];
  float* out = (float*)d_out;

  char* ws = (char*)d_ws;
  // layout (Q aliases P: P dead after gather1, gemm_Q runs after):
  short* P   = (short*)(ws);                    // 100032*256*2 = 51,216,384
  short* Q   = (short*)(ws);                    // 40960*256*2  = 20,971,520 (alias)
  short* h1  = (short*)(ws + 51216384);         // 40960*128*2  = 10,485,760
  short* W1b = (short*)(ws + 61702144);         // 131,072
  short* W2b = (short*)(ws + 61833216);         // 65,536
                                                // total 61,898,752 bytes

  cvt_weights<<<256, 256, 0, stream>>>(W1, W2, W1b, W2b);
  gemm_P<<<MPAD / 64, 256, 0, stream>>>(raw, W1b, P);
  gather1<<<N1N / 16, 256, 0, stream>>>(P, nodes1, neighs1, h1);
  gemm_Q<<<N1N / 64, 256, 0, stream>>>(h1, W2b, Q);
  gather2<<<BATCH / 16, 256, 0, stream>>>(Q, map2, neighs2, out);
}

// Round 3
// 93.221 us; speedup vs baseline: 1.9176x; 1.9176x over previous
//
#include <hip/hip_runtime.h>
#include <hip/hip_bf16.h>

#define N_RAW  100000
#define DIM    256
#define OUTD   128
#define KN     10
#define N1N    40960
#define BATCH  4096

typedef __attribute__((ext_vector_type(8))) short bf16x8;
typedef __attribute__((ext_vector_type(4))) float f32x4;
typedef unsigned int u32;

static __device__ inline float b2f(short s) {
  unsigned u = ((unsigned)(unsigned short)s) << 16;
  return __builtin_bit_cast(float, u);
}
static __device__ inline short f2b(float f) {
  unsigned u = __builtin_bit_cast(unsigned, f);
  unsigned r = (u + 0x7fff + ((u >> 16) & 1)) >> 16;  // RNE
  return (short)r;
}

static __device__ inline void gload_lds16(const void* g, void* l) {
  __builtin_amdgcn_global_load_lds((const __attribute__((address_space(1))) u32*)g,
                                   (__attribute__((address_space(3))) u32*)l, 16, 0, 0);
}

// ---- build combined weights, bf16, PRE-SWIZZLED image (byte ^= (row&7)<<4) ----
// W1c[256][256]: row j<128 -> W1[j][0:256] (self), j>=128 -> W1[j-128][256:512] (agg)
// W2c[256][128]: row j<128 -> W2[j][0:128] (self), j>=128 -> W2[j-128][128:256] (agg)
__global__ void build_wc(const float* __restrict__ W1, const float* __restrict__ W2,
                         short* __restrict__ W1c, short* __restrict__ W2c) {
  int i = blockIdx.x * blockDim.x + threadIdx.x;   // 65536 total
  {
    int j = i >> 8, k = i & 255;
    float v = (j < OUTD) ? W1[j * (2 * DIM) + k] : W1[(j - OUTD) * (2 * DIM) + DIM + k];
    u32 byte = (u32)(j * 512 + k * 2) ^ ((u32)(j & 7) << 4);
    *(short*)((char*)W1c + byte) = f2b(v);
  }
  if (i < 256 * 128) {
    int j = i >> 7, k = i & 127;
    float v = (j < OUTD) ? W2[j * (2 * OUTD) + k] : W2[(j - OUTD) * (2 * OUTD) + OUTD + k];
    u32 byte = (u32)(j * 256 + k * 2) ^ ((u32)(j & 7) << 4);
    *(short*)((char*)W2c + byte) = f2b(v);
  }
}

// ---- P[100000,256] = raw[100000,256]_f32 @ W1c^T (bf16 out) ----
// 8 waves, block = 128 rows x 256 cols, full W1c (128 KB) in LDS.
// mfma_f32_16x16x32_bf16 frags (m89/m91): A row=lane&15 k=(lane>>4)*8+e;
// B col=lane&15 same k; D col=lane&15 row=(lane>>4)*4+e.
__launch_bounds__(512, 2)
__global__ void gemm_P(const float* __restrict__ raw, const short* __restrict__ W1c,
                       short* __restrict__ P) {
  __shared__ short Wlds[256 * 256];   // 128 KB, holds swizzled W1c image verbatim
  const int tid  = threadIdx.x;
  const int wave = tid >> 6, lane = tid & 63;
  const int r16  = lane & 15, kg = lane >> 4;
  const int m0   = blockIdx.x * 128 + wave * 16;

  // A prefetch: full K row per lane, 16 independent dwordx4 loads
  int arow = m0 + r16; if (arow >= N_RAW) arow = N_RAW - 1;
  const float* xrow = raw + (size_t)arow * DIM + kg * 8;
  float4 af[16];
#pragma unroll
  for (int ks = 0; ks < 8; ++ks) {
    af[2 * ks]     = *(const float4*)(xrow + ks * 32);
    af[2 * ks + 1] = *(const float4*)(xrow + ks * 32 + 4);
  }

  // stage 128 KB: 16 iters x (512 lanes x 16 B); dest wave-uniform base + lane*16
#pragma unroll
  for (int it = 0; it < 16; ++it)
    gload_lds16((const char*)W1c + it * 8192 + tid * 16,
                (char*)Wlds + it * 8192 + wave * 1024);
  __syncthreads();   // drains vmcnt (staging + A loads)

  bf16x8 ab[8];
#pragma unroll
  for (int ks = 0; ks < 8; ++ks) {
    bf16x8 t;
    t[0] = f2b(af[2 * ks].x);     t[1] = f2b(af[2 * ks].y);
    t[2] = f2b(af[2 * ks].z);     t[3] = f2b(af[2 * ks].w);
    t[4] = f2b(af[2 * ks + 1].x); t[5] = f2b(af[2 * ks + 1].y);
    t[6] = f2b(af[2 * ks + 1].z); t[7] = f2b(af[2 * ks + 1].w);
    ab[ks] = t;
  }

  f32x4 acc[16];
#pragma unroll
  for (int n = 0; n < 16; ++n) acc[n] = (f32x4){0.f, 0.f, 0.f, 0.f};

#pragma unroll
  for (int ks = 0; ks < 8; ++ks) {
#pragma unroll
    for (int n = 0; n < 16; ++n) {
      u32 byte = (u32)((n * 16 + r16) * 512 + ks * 64 + kg * 16) ^ ((u32)(r16 & 7) << 4);
      bf16x8 b = *(const bf16x8*)((const char*)Wlds + byte);  // ds_read_b128
      acc[n] = __builtin_amdgcn_mfma_f32_16x16x32_bf16(ab[ks], b, acc[n], 0, 0, 0);
    }
  }

#pragma unroll
  for (int n = 0; n < 16; ++n)
#pragma unroll
    for (int j = 0; j < 4; ++j) {
      int r = m0 + kg * 4 + j;
      if (r < N_RAW) P[(size_t)r * 256 + (n * 16 + r16)] = f2b(acc[n][j]);
    }
}

// ---- Q[40960,256] = h1[40960,128]_bf16 @ W2c^T (bf16 out) ----
__launch_bounds__(512, 4)
__global__ void gemm_Q(const short* __restrict__ h1, const short* __restrict__ W2c,
                       short* __restrict__ Q) {
  __shared__ short Wlds[256 * 128];   // 64 KB
  const int tid  = threadIdx.x;
  const int wave = tid >> 6, lane = tid & 63;
  const int r16  = lane & 15, kg = lane >> 4;
  const int m0   = blockIdx.x * 128 + wave * 16;

  const short* xrow = h1 + (size_t)(m0 + r16) * OUTD + kg * 8;
  bf16x8 ab[4];
#pragma unroll
  for (int ks = 0; ks < 4; ++ks) ab[ks] = *(const bf16x8*)(xrow + ks * 32);

#pragma unroll
  for (int it = 0; it < 8; ++it)
    gload_lds16((const char*)W2c + it * 8192 + tid * 16,
                (char*)Wlds + it * 8192 + wave * 1024);
  __syncthreads();

  f32x4 acc[16];
#pragma unroll
  for (int n = 0; n < 16; ++n) acc[n] = (f32x4){0.f, 0.f, 0.f, 0.f};

#pragma unroll
  for (int ks = 0; ks < 4; ++ks) {
#pragma unroll
    for (int n = 0; n < 16; ++n) {
      u32 byte = (u32)((n * 16 + r16) * 256 + ks * 64 + kg * 16) ^ ((u32)(r16 & 7) << 4);
      bf16x8 b = *(const bf16x8*)((const char*)Wlds + byte);
      acc[n] = __builtin_amdgcn_mfma_f32_16x16x32_bf16(ab[ks], b, acc[n], 0, 0, 0);
    }
  }

#pragma unroll
  for (int n = 0; n < 16; ++n)
#pragma unroll
    for (int j = 0; j < 4; ++j)
      Q[(size_t)(m0 + kg * 4 + j) * 256 + (n * 16 + r16)] = f2b(acc[n][j]);
}

// ---- h1[i] = relu(P[nodes1[i]][0:128] + 0.1 * sum_k P[neighs1[i,k]][128:256]) ----
__global__ void gather1(const short* __restrict__ P, const int* __restrict__ nodes1,
                        const int* __restrict__ neighs1, short* __restrict__ h1) {
  int g = threadIdx.x >> 4, t = threadIdx.x & 15;
  int row = blockIdx.x * 16 + g;
  int sn = nodes1[row];
  bf16x8 sv = *(const bf16x8*)(P + (size_t)sn * 256 + t * 8);
  float acc[8];
#pragma unroll
  for (int e = 0; e < 8; ++e) acc[e] = 0.f;
#pragma unroll
  for (int k = 0; k < KN; ++k) {
    int nn = neighs1[row * KN + k];
    bf16x8 nv = *(const bf16x8*)(P + (size_t)nn * 256 + 128 + t * 8);
#pragma unroll
    for (int e = 0; e < 8; ++e) acc[e] += b2f(nv[e]);
  }
  bf16x8 o;
#pragma unroll
  for (int e = 0; e < 8; ++e) o[e] = f2b(fmaxf(b2f(sv[e]) + 0.1f * acc[e], 0.f));
  *(bf16x8*)(h1 + (size_t)row * OUTD + t * 8) = o;
}

// ---- out[i] = relu(Q[map2[i]][0:128] + 0.1 * sum_k Q[neighs2[i,k]][128:256]) f32 ----
__global__ void gather2(const short* __restrict__ Q, const int* __restrict__ map2,
                        const int* __restrict__ neighs2, float* __restrict__ out) {
  int g = threadIdx.x >> 4, t = threadIdx.x & 15;
  int row = blockIdx.x * 16 + g;
  int sn = map2[row];
  bf16x8 sv = *(const bf16x8*)(Q + (size_t)sn * 256 + t * 8);
  float acc[8];
#pragma unroll
  for (int e = 0; e < 8; ++e) acc[e] = 0.f;
#pragma unroll
  for (int k = 0; k < KN; ++k) {
    int nn = neighs2[row * KN + k];
    bf16x8 nv = *(const bf16x8*)(Q + (size_t)nn * 256 + 128 + t * 8);
#pragma unroll
    for (int e = 0; e < 8; ++e) acc[e] += b2f(nv[e]);
  }
  float* orow = out + (size_t)row * OUTD + t * 8;
  float4 o0, o1;
  o0.x = fmaxf(b2f(sv[0]) + 0.1f * acc[0], 0.f);
  o0.y = fmaxf(b2f(sv[1]) + 0.1f * acc[1], 0.f);
  o0.z = fmaxf(b2f(sv[2]) + 0.1f * acc[2], 0.f);
  o0.w = fmaxf(b2f(sv[3]) + 0.1f * acc[3], 0.f);
  o1.x = fmaxf(b2f(sv[4]) + 0.1f * acc[4], 0.f);
  o1.y = fmaxf(b2f(sv[5]) + 0.1f * acc[5], 0.f);
  o1.z = fmaxf(b2f(sv[6]) + 0.1f * acc[6], 0.f);
  o1.w = fmaxf(b2f(sv[7]) + 0.1f * acc[7], 0.f);
  *(float4*)orow = o0;
  *(float4*)(orow + 4) = o1;
}

extern "C" void kernel_launch(void* const* d_in, const int* in_sizes, int n_in,
                              void* d_out, int out_size, void* d_ws, size_t ws_size,
                              hipStream_t stream) {
  const float* raw     = (const float*)d_in[0];
  const float* W1      = (const float*)d_in[1];
  const float* W2      = (const float*)d_in[2];
  const int*   nodes1  = (const int*)d_in[3];
  const int*   neighs1 = (const int*)d_in[4];
  const int*   map2    = (const int*)d_in[5];
  const int*   neighs2 = (const int*)d_in[6];
  float* out = (float*)d_out;

  char* ws = (char*)d_ws;
  short* W1c = (short*)(ws);                 // 131,072 B
  short* W2c = (short*)(ws + 131072);        //  65,536 B
  short* P   = (short*)(ws + 196608);        // 100000*256*2 = 51,200,000 B
  short* Q   = (short*)(ws + 196608);        // alias (P dead after gather1)
  short* h1  = (short*)(ws + 51396608);      // 40960*128*2 = 10,485,760 B
                                             // total 61,882,368 B

  build_wc<<<256, 256, 0, stream>>>(W1, W2, W1c, W2c);
  gemm_P<<<782, 512, 0, stream>>>(raw, W1c, P);             // 782*128 >= 100000
  gather1<<<N1N / 16, 256, 0, stream>>>(P, nodes1, neighs1, h1);
  gemm_Q<<<N1N / 128, 512, 0, stream>>>(h1, W2c, Q);
  gather2<<<BATCH / 16, 256, 0, stream>>>(Q, map2, neighs2, out);
}

// Round 4
// 91.537 us; speedup vs baseline: 1.9529x; 1.0184x over previous
//
#include <hip/hip_runtime.h>
#include <hip/hip_bf16.h>

#define N_RAW  100000
#define DIM    256
#define OUTD   128
#define KN     10
#define N1N    40960
#define BATCH  4096

typedef __attribute__((ext_vector_type(8))) short bf16x8;
typedef __attribute__((ext_vector_type(4))) float f32x4;
typedef unsigned int u32;

static __device__ inline float b2f(short s) {
  unsigned u = ((unsigned)(unsigned short)s) << 16;
  return __builtin_bit_cast(float, u);
}
static __device__ inline short f2b(float f) {
  unsigned u = __builtin_bit_cast(unsigned, f);
  unsigned r = (u + 0x7fff + ((u >> 16) & 1)) >> 16;  // RNE
  return (short)r;
}

static __device__ inline void gload_lds16(const void* g, void* l) {
  __builtin_amdgcn_global_load_lds((const __attribute__((address_space(1))) u32*)g,
                                   (__attribute__((address_space(3))) u32*)l, 16, 0, 0);
}

// ---- build combined weights, bf16, pre-swizzled ----
// W1c: TWO half-images of 64 KB (half h = K cols [h*128,(h+1)*128)), each
//   [256 rows][128 cols] with byte ^= (row&7)<<4  (matches gemm_P's LDS reads).
// W2c: one 64 KB image [256 rows][128 cols], same swizzle (gemm_Q unchanged).
__global__ void build_wc(const float* __restrict__ W1, const float* __restrict__ W2,
                         short* __restrict__ W1c, short* __restrict__ W2c) {
  int i = blockIdx.x * blockDim.x + threadIdx.x;   // 65536 total
  {
    int j = i >> 8, k = i & 255;
    float v = (j < OUTD) ? W1[j * (2 * DIM) + k] : W1[(j - OUTD) * (2 * DIM) + DIM + k];
    int h = k >> 7, kk = k & 127;
    u32 byte = (u32)(h * 65536) + (((u32)(j * 256 + kk * 2)) ^ ((u32)(j & 7) << 4));
    *(short*)((char*)W1c + byte) = f2b(v);
  }
  if (i < 256 * 128) {
    int j = i >> 7, k = i & 127;
    float v = (j < OUTD) ? W2[j * (2 * OUTD) + k] : W2[(j - OUTD) * (2 * OUTD) + OUTD + k];
    u32 byte = (u32)(j * 256 + k * 2) ^ ((u32)(j & 7) << 4);
    *(short*)((char*)W2c + byte) = f2b(v);
  }
}

// ---- P[100000,256] = raw[100000,256]_f32 @ W1c^T (bf16 out) ----
// 4 waves/block, block tile 128 rows x 256 cols; wave tile 32 rows (M_rep=2).
// K split in two 64 KB LDS halves -> 2 blocks/CU, cross-block overlap.
// mfma_f32_16x16x32_bf16 frags (m89/m91): A row=lane&15 k=(lane>>4)*8+e;
// B col=lane&15 same k; D col=lane&15 row=(lane>>4)*4+e.
__launch_bounds__(256, 2)
__global__ void gemm_P(const float* __restrict__ raw, const short* __restrict__ W1c,
                       short* __restrict__ P) {
  __shared__ short Bh[256 * 128];   // 64 KB, swizzled half-image verbatim
  const int tid  = threadIdx.x;
  const int wave = tid >> 6, lane = tid & 63;
  const int r16  = lane & 15, kg = lane >> 4;
  const int m0   = blockIdx.x * 128 + wave * 32;

  int r0 = m0 + r16;      if (r0 > N_RAW - 1) r0 = N_RAW - 1;
  int r1 = m0 + 16 + r16; if (r1 > N_RAW - 1) r1 = N_RAW - 1;
  const float* x0 = raw + (size_t)r0 * DIM + kg * 8;
  const float* x1 = raw + (size_t)r1 * DIM + kg * 8;

  // issue A(h0) loads: 16 independent dwordx4
  float4 af[16];
#pragma unroll
  for (int ks = 0; ks < 4; ++ks) {
    af[ks * 2]         = *(const float4*)(x0 + ks * 32);
    af[ks * 2 + 1]     = *(const float4*)(x0 + ks * 32 + 4);
    af[8 + ks * 2]     = *(const float4*)(x1 + ks * 32);
    af[8 + ks * 2 + 1] = *(const float4*)(x1 + ks * 32 + 4);
  }

  // stage B(h0): 64 KB, linear copy of pre-swizzled image
#pragma unroll
  for (int it = 0; it < 16; ++it)
    gload_lds16((const char*)W1c + it * 4096 + tid * 16,
                (char*)Bh + it * 4096 + wave * 1024);

  // convert A(h0) while staging is in flight (A loads are older on vmcnt)
  bf16x8 a0[2][4];
#pragma unroll
  for (int s = 0; s < 2; ++s)
#pragma unroll
    for (int ks = 0; ks < 4; ++ks) {
      float4 lo = af[s * 8 + ks * 2], hi = af[s * 8 + ks * 2 + 1];
      bf16x8 t;
      t[0] = f2b(lo.x); t[1] = f2b(lo.y); t[2] = f2b(lo.z); t[3] = f2b(lo.w);
      t[4] = f2b(hi.x); t[5] = f2b(hi.y); t[6] = f2b(hi.z); t[7] = f2b(hi.w);
      a0[s][ks] = t;
    }

  f32x4 acc[2][16];
#pragma unroll
  for (int s = 0; s < 2; ++s)
#pragma unroll
    for (int n = 0; n < 16; ++n) acc[s][n] = (f32x4){0.f, 0.f, 0.f, 0.f};

  __syncthreads();

  // issue A(h1) loads now — latency hides under compute(h0)
#pragma unroll
  for (int ks = 0; ks < 4; ++ks) {
    af[ks * 2]         = *(const float4*)(x0 + 128 + ks * 32);
    af[ks * 2 + 1]     = *(const float4*)(x0 + 128 + ks * 32 + 4);
    af[8 + ks * 2]     = *(const float4*)(x1 + 128 + ks * 32);
    af[8 + ks * 2 + 1] = *(const float4*)(x1 + 128 + ks * 32 + 4);
  }

  // compute h0: 64 ds_read_b128 + 128 MFMA per wave
#pragma unroll
  for (int ks = 0; ks < 4; ++ks)
#pragma unroll
    for (int n = 0; n < 16; ++n) {
      u32 byte = (u32)((n * 16 + r16) * 256 + ks * 64 + kg * 16) ^ ((u32)(r16 & 7) << 4);
      bf16x8 b = *(const bf16x8*)((const char*)Bh + byte);
      acc[0][n] = __builtin_amdgcn_mfma_f32_16x16x32_bf16(a0[0][ks], b, acc[0][n], 0, 0, 0);
      acc[1][n] = __builtin_amdgcn_mfma_f32_16x16x32_bf16(a0[1][ks], b, acc[1][n], 0, 0, 0);
    }

  __syncthreads();   // all waves done reading h0 LDS

  // stage B(h1)
#pragma unroll
  for (int it = 0; it < 16; ++it)
    gload_lds16((const char*)W1c + 65536 + it * 4096 + tid * 16,
                (char*)Bh + it * 4096 + wave * 1024);

  // convert A(h1) (waits its loads; they were issued long ago)
#pragma unroll
  for (int s = 0; s < 2; ++s)
#pragma unroll
    for (int ks = 0; ks < 4; ++ks) {
      float4 lo = af[s * 8 + ks * 2], hi = af[s * 8 + ks * 2 + 1];
      bf16x8 t;
      t[0] = f2b(lo.x); t[1] = f2b(lo.y); t[2] = f2b(lo.z); t[3] = f2b(lo.w);
      t[4] = f2b(hi.x); t[5] = f2b(hi.y); t[6] = f2b(hi.z); t[7] = f2b(hi.w);
      a0[s][ks] = t;
    }

  __syncthreads();

  // compute h1
#pragma unroll
  for (int ks = 0; ks < 4; ++ks)
#pragma unroll
    for (int n = 0; n < 16; ++n) {
      u32 byte = (u32)((n * 16 + r16) * 256 + ks * 64 + kg * 16) ^ ((u32)(r16 & 7) << 4);
      bf16x8 b = *(const bf16x8*)((const char*)Bh + byte);
      acc[0][n] = __builtin_amdgcn_mfma_f32_16x16x32_bf16(a0[0][ks], b, acc[0][n], 0, 0, 0);
      acc[1][n] = __builtin_amdgcn_mfma_f32_16x16x32_bf16(a0[1][ks], b, acc[1][n], 0, 0, 0);
    }

  // epilogue
#pragma unroll
  for (int s = 0; s < 2; ++s)
#pragma unroll
    for (int n = 0; n < 16; ++n)
#pragma unroll
      for (int j = 0; j < 4; ++j) {
        int r = m0 + s * 16 + kg * 4 + j;
        if (r < N_RAW) P[(size_t)r * 256 + (n * 16 + r16)] = f2b(acc[s][n][j]);
      }
}

// ---- Q[40960,256] = h1[40960,128]_bf16 @ W2c^T (bf16 out) ----
__launch_bounds__(512, 4)
__global__ void gemm_Q(const short* __restrict__ h1, const short* __restrict__ W2c,
                       short* __restrict__ Q) {
  __shared__ short Wlds[256 * 128];   // 64 KB
  const int tid  = threadIdx.x;
  const int wave = tid >> 6, lane = tid & 63;
  const int r16  = lane & 15, kg = lane >> 4;
  const int m0   = blockIdx.x * 128 + wave * 16;

  const short* xrow = h1 + (size_t)(m0 + r16) * OUTD + kg * 8;
  bf16x8 ab[4];
#pragma unroll
  for (int ks = 0; ks < 4; ++ks) ab[ks] = *(const bf16x8*)(xrow + ks * 32);

#pragma unroll
  for (int it = 0; it < 8; ++it)
    gload_lds16((const char*)W2c + it * 8192 + tid * 16,
                (char*)Wlds + it * 8192 + wave * 1024);
  __syncthreads();

  f32x4 acc[16];
#pragma unroll
  for (int n = 0; n < 16; ++n) acc[n] = (f32x4){0.f, 0.f, 0.f, 0.f};

#pragma unroll
  for (int ks = 0; ks < 4; ++ks) {
#pragma unroll
    for (int n = 0; n < 16; ++n) {
      u32 byte = (u32)((n * 16 + r16) * 256 + ks * 64 + kg * 16) ^ ((u32)(r16 & 7) << 4);
      bf16x8 b = *(const bf16x8*)((const char*)Wlds + byte);
      acc[n] = __builtin_amdgcn_mfma_f32_16x16x32_bf16(ab[ks], b, acc[n], 0, 0, 0);
    }
  }

#pragma unroll
  for (int n = 0; n < 16; ++n)
#pragma unroll
    for (int j = 0; j < 4; ++j)
      Q[(size_t)(m0 + kg * 4 + j) * 256 + (n * 16 + r16)] = f2b(acc[n][j]);
}

// ---- h1[i] = relu(P[nodes1[i]][0:128] + 0.1 * sum_k P[neighs1[i,k]][128:256]) ----
__global__ void gather1(const short* __restrict__ P, const int* __restrict__ nodes1,
                        const int* __restrict__ neighs1, short* __restrict__ h1) {
  int g = threadIdx.x >> 4, t = threadIdx.x & 15;
  int row = blockIdx.x * 16 + g;
  int sn = nodes1[row];
  bf16x8 sv = *(const bf16x8*)(P + (size_t)sn * 256 + t * 8);
  float acc[8];
#pragma unroll
  for (int e = 0; e < 8; ++e) acc[e] = 0.f;
#pragma unroll
  for (int k = 0; k < KN; ++k) {
    int nn = neighs1[row * KN + k];
    bf16x8 nv = *(const bf16x8*)(P + (size_t)nn * 256 + 128 + t * 8);
#pragma unroll
    for (int e = 0; e < 8; ++e) acc[e] += b2f(nv[e]);
  }
  bf16x8 o;
#pragma unroll
  for (int e = 0; e < 8; ++e) o[e] = f2b(fmaxf(b2f(sv[e]) + 0.1f * acc[e], 0.f));
  *(bf16x8*)(h1 + (size_t)row * OUTD + t * 8) = o;
}

// ---- out[i] = relu(Q[map2[i]][0:128] + 0.1 * sum_k Q[neighs2[i,k]][128:256]) f32 ----
__global__ void gather2(const short* __restrict__ Q, const int* __restrict__ map2,
                        const int* __restrict__ neighs2, float* __restrict__ out) {
  int g = threadIdx.x >> 4, t = threadIdx.x & 15;
  int row = blockIdx.x * 16 + g;
  int sn = map2[row];
  bf16x8 sv = *(const bf16x8*)(Q + (size_t)sn * 256 + t * 8);
  float acc[8];
#pragma unroll
  for (int e = 0; e < 8; ++e) acc[e] = 0.f;
#pragma unroll
  for (int k = 0; k < KN; ++k) {
    int nn = neighs2[row * KN + k];
    bf16x8 nv = *(const bf16x8*)(Q + (size_t)nn * 256 + 128 + t * 8);
#pragma unroll
    for (int e = 0; e < 8; ++e) acc[e] += b2f(nv[e]);
  }
  float* orow = out + (size_t)row * OUTD + t * 8;
  float4 o0, o1;
  o0.x = fmaxf(b2f(sv[0]) + 0.1f * acc[0], 0.f);
  o0.y = fmaxf(b2f(sv[1]) + 0.1f * acc[1], 0.f);
  o0.z = fmaxf(b2f(sv[2]) + 0.1f * acc[2], 0.f);
  o0.w = fmaxf(b2f(sv[3]) + 0.1f * acc[3], 0.f);
  o1.x = fmaxf(b2f(sv[4]) + 0.1f * acc[4], 0.f);
  o1.y = fmaxf(b2f(sv[5]) + 0.1f * acc[5], 0.f);
  o1.z = fmaxf(b2f(sv[6]) + 0.1f * acc[6], 0.f);
  o1.w = fmaxf(b2f(sv[7]) + 0.1f * acc[7], 0.f);
  *(float4*)orow = o0;
  *(float4*)(orow + 4) = o1;
}

extern "C" void kernel_launch(void* const* d_in, const int* in_sizes, int n_in,
                              void* d_out, int out_size, void* d_ws, size_t ws_size,
                              hipStream_t stream) {
  const float* raw     = (const float*)d_in[0];
  const float* W1      = (const float*)d_in[1];
  const float* W2      = (const float*)d_in[2];
  const int*   nodes1  = (const int*)d_in[3];
  const int*   neighs1 = (const int*)d_in[4];
  const int*   map2    = (const int*)d_in[5];
  const int*   neighs2 = (const int*)d_in[6];
  float* out = (float*)d_out;

  char* ws = (char*)d_ws;
  short* W1c = (short*)(ws);                 // 131,072 B (two 64 KB half-images)
  short* W2c = (short*)(ws + 131072);        //  65,536 B
  short* P   = (short*)(ws + 196608);        // 100000*256*2 = 51,200,000 B
  short* Q   = (short*)(ws + 196608);        // alias (P dead after gather1)
  short* h1  = (short*)(ws + 51396608);      // 40960*128*2 = 10,485,760 B
                                             // total 61,882,368 B

  build_wc<<<256, 256, 0, stream>>>(W1, W2, W1c, W2c);
  gemm_P<<<782, 256, 0, stream>>>(raw, W1c, P);             // 782*128 >= 100000
  gather1<<<N1N / 16, 256, 0, stream>>>(P, nodes1, neighs1, h1);
  gemm_Q<<<N1N / 128, 512, 0, stream>>>(h1, W2c, Q);
  gather2<<<BATCH / 16, 256, 0, stream>>>(Q, map2, neighs2, out);
}